// Round 10
// baseline (63.701 us; speedup 1.0000x reference)
//
#include <hip/hip_runtime.h>
#include <hip/hip_bf16.h>

#define EPS   1e-07f
#define ONEPS (1.0f + 1e-07f)

// Clang native vectors: indexable, and __builtin_nontemporal_* accepts them.
typedef int          iv4 __attribute__((ext_vector_type(4)));
typedef float        fv4 __attribute__((ext_vector_type(4)));
typedef unsigned int uv4 __attribute__((ext_vector_type(4)));

// Geometry: bucket b covers output region [b*REG, (b+1)*REG).
#define NB        512            // buckets (= out_size / REG)
#define REG       65536          // elements per region (offset fits in ushort)
#define SEGCAP    128            // entries per (block,bucket) segment (global layout)
#define SEGSTRIDE 136            // LDS stage stride in ushorts (bank spread; R9-proven)

#define PA_BLOCK 1024            // threads (16 waves)
#define PA_CHUNK 32768           // indices per bin block
#define PA_NBLK  512             // 16777216 / 32768

#define PB_BLOCK 512             // 8 waves; 8.7 KB LDS -> 4 blocks/CU (32 waves)

// ws layout:
//   [0, COUNTS_BYTES)                      : counts_u8[b*PA_NBLK + blk]  (256 KB)
//   [COUNTS_BYTES, +NB*PA_NBLK*SEGCAP*2)   : buckets ushort, [b][blk][SEGCAP] (64 MB)
#define COUNTS_BYTES ((size_t)NB * PA_NBLK)
#define WS_NEEDED    (COUNTS_BYTES + (size_t)NB * PA_NBLK * SEGCAP * 2)

// ---------------- Pass A: single-pass binning into fixed segments -----------
// 139 KB stage + 2 KB cursors -> 1 block/CU, 16 waves/CU. No hist/scan/global
// atomics. Last uint4 of each segment tail-patched with the segment's first
// entry (duplicates harmless) so expand reads count-limited uint4s unmasked.
__global__ __launch_bounds__(PA_BLOCK) void bin_kernel(
    const int* __restrict__ idx,
    unsigned short* __restrict__ buckets,
    unsigned char* __restrict__ counts)
{
    __shared__ __align__(16) unsigned short stage[NB * SEGSTRIDE];  // 139 KB
    __shared__ int cursor[NB];                                      // 2 KB

    const int t   = threadIdx.x;
    const int blk = blockIdx.x;

    if (t < NB) cursor[t] = 0;
    __syncthreads();

    // 8 iv4 loads per thread, nontemporal (read-once stream).
    const iv4* idx4 = (const iv4*)(idx + (size_t)blk * PA_CHUNK);
#pragma unroll 8
    for (int r = 0; r < PA_CHUNK / (PA_BLOCK * 4); ++r) {   // 8 iters
        iv4 q = __builtin_nontemporal_load(&idx4[r * PA_BLOCK + t]);
#pragma unroll
        for (int j = 0; j < 4; ++j) {
            int vj = q[j];
            int b = vj >> 16;
            int p = atomicAdd(&cursor[b], 1);
            if (p < SEGCAP)
                stage[b * SEGSTRIDE + p] = (unsigned short)(vj & 0xFFFF);
        }
    }
    __syncthreads();

    // counts TRANSPOSED to [b][blk]: scattered byte stores (fire-and-forget,
    // no dependency) so expand's read is fully coalesced.
    if (t < NB) {
        int n_t = cursor[t];
        if (n_t > SEGCAP) n_t = SEGCAP;
        counts[(size_t)t * PA_NBLK + blk] = (unsigned char)n_t;
    }

    // copy-out: 4 buckets per wave (16-lane groups), uint4 stores, last-uint4
    // tail patched with the segment's first entry.
    const int w   = t >> 6;          // wave id, 16 waves
    const int sub = (t >> 4) & 3;    // bucket-subgroup within wave
    const int l16 = t & 15;          // lane within 16-group
    for (int i = 0; i < NB / 64; ++i) {
        int b = i * 64 + w * 4 + sub;
        int n = cursor[b];
        if (n > SEGCAP) n = SEGCAP;
        int nu4 = (n + 7) >> 3;      // uint4's needed (<= 16)
        uv4* dst = (uv4*)(buckets + ((size_t)b * PA_NBLK + blk) * SEGCAP);
        const uv4* srcp = (const uv4*)(stage + b * SEGSTRIDE);
        if (l16 < nu4) {
            uv4 u = srcp[l16];
            if (l16 == nu4 - 1 && (n & 7)) {
                unsigned int e0  = stage[b * SEGSTRIDE];   // LDS broadcast read
                unsigned int e00 = e0 | (e0 << 16);
                int base = l16 * 8;
#pragma unroll
                for (int k = 0; k < 4; ++k) {
                    unsigned int wv = u[k];
                    int i0 = base + 2 * k;
                    if (i0 + 1 >= n) wv = (wv & 0xFFFFu) | (e0 << 16);
                    if (i0     >= n) wv = e00;
                    u[k] = wv;
                }
            }
            dst[l16] = u;
        }
    }
}

// ---------------- Pass B: LDS bitmap per region, streamed output ------------
// 8.7 KB LDS, 512 threads -> 4 blocks/CU, 32 waves/CU: cross-block phase
// desync overlaps one block's LDS marking with another's output stream.
// Count-aware uint4 reads (all 8 entries valid, bin pad-patched).
__global__ __launch_bounds__(PB_BLOCK) void expand_kernel(
    const unsigned short* __restrict__ buckets,
    const unsigned char* __restrict__ counts,
    float* __restrict__ out)
{
    __shared__ unsigned int bm[REG / 32];           // 8 KB bitmap
    __shared__ unsigned char cnt[PA_NBLK];          // 512 B

    const int t = threadIdx.x;
    const int b = blockIdx.x;

    // zero bitmap: 512 uint4 stores across 512 threads.
    ((uint4*)bm)[t] = make_uint4(0u, 0u, 0u, 0u);
    // coalesced count load: 512 B as 128 uints.
    if (t < PA_NBLK / 4)
        ((unsigned int*)cnt)[t] =
            ((const unsigned int*)(counts + (size_t)b * PA_NBLK))[t];
    __syncthreads();

    // 512 segments, 32 groups of 16 lanes -> 16 rounds. Marks via no-return
    // LDS atomicOr (random words over 2048 -> rare collisions).
    const uv4* src4 = (const uv4*)(buckets + (size_t)b * PA_NBLK * SEGCAP);
    const int g   = t >> 4;
    const int l16 = t & 15;
#pragma unroll
    for (int r = 0; r < PA_NBLK / 32; ++r) {
        int seg = r * 32 + g;
        int nu4 = ((int)cnt[seg] + 7) >> 3;
        if (l16 < nu4) {
            uv4 u = src4[seg * (SEGCAP / 8) + l16];
#pragma unroll
            for (int k = 0; k < 4; ++k) {
                unsigned int wv = u[k];
                unsigned int e0 = wv & 0xFFFFu;
                unsigned int e1 = wv >> 16;
                atomicOr(&bm[e0 >> 5], 1u << (e0 & 31));
                atomicOr(&bm[e1 >> 5], 1u << (e1 & 31));
            }
        }
    }
    __syncthreads();

    // output: one bitmap word per 8 float4s; consecutive 8 lanes share a word
    // (LDS broadcast). 32 nt float4 stores per thread.
    fv4* o = (fv4*)(out + (size_t)b * REG);
#pragma unroll 4
    for (int i = t; i < REG / 4; i += PB_BLOCK) {
        unsigned int wv = bm[i >> 3];
        int s = (i & 7) * 4;
        fv4 f;
        f.x = ((wv >> (s + 0)) & 1u) ? ONEPS : EPS;
        f.y = ((wv >> (s + 1)) & 1u) ? ONEPS : EPS;
        f.z = ((wv >> (s + 2)) & 1u) ? ONEPS : EPS;
        f.w = ((wv >> (s + 3)) & 1u) ? ONEPS : EPS;
        __builtin_nontemporal_store(f, &o[i]);      // write-once stream
    }
}

// ---------------- fallback path (proven in round 1) -------------------------
__global__ void fill_eps_kernel(float4* __restrict__ out, int n4) {
    int stride = gridDim.x * blockDim.x;
    const float4 v = make_float4(EPS, EPS, EPS, EPS);
    for (int i = blockIdx.x * blockDim.x + threadIdx.x; i < n4; i += stride)
        out[i] = v;
}

__global__ void scatter_ones_kernel(const int4* __restrict__ idx,
                                    float* __restrict__ out, int n4) {
    int i = blockIdx.x * blockDim.x + threadIdx.x;
    if (i < n4) {
        int4 v = idx[i];
        out[v.x] = ONEPS;
        out[v.y] = ONEPS;
        out[v.z] = ONEPS;
        out[v.w] = ONEPS;
    }
}

extern "C" void kernel_launch(void* const* d_in, const int* in_sizes, int n_in,
                              void* d_out, int out_size, void* d_ws, size_t ws_size,
                              hipStream_t stream) {
    // inputs: [0] voxel (float32, 256^3) -- values irrelevant to output
    //         [1] cell_indices (int32, 256^3)
    //         [2] num_elements (scalar)  -- use out_size instead
    const int* cell_indices = (const int*)d_in[1];
    const int n_idx = in_sizes[1];                   // 16777216

    if (out_size == NB * REG && n_idx == PA_NBLK * PA_CHUNK &&
        ws_size >= WS_NEEDED) {
        unsigned char* counts = (unsigned char*)d_ws;
        unsigned short* buckets =
            (unsigned short*)((char*)d_ws + COUNTS_BYTES);

        // Every counts/bucket slot consumed by expand is written by bin every
        // call -> no zeroing needed, deterministic across replays.
        bin_kernel<<<PA_NBLK, PA_BLOCK, 0, stream>>>(
            cell_indices, buckets, counts);

        expand_kernel<<<NB, PB_BLOCK, 0, stream>>>(
            buckets, counts, (float*)d_out);
    } else {
        // fallback: direct scatter (round-1 behavior)
        int n4_fill = out_size >> 2;
        fill_eps_kernel<<<2048, 256, 0, stream>>>((float4*)d_out, n4_fill);
        int n4_idx = n_idx >> 2;
        int blocks = (n4_idx + 255) / 256;
        scatter_ones_kernel<<<blocks, 256, 0, stream>>>(
            (const int4*)cell_indices, (float*)d_out, n4_idx);
    }
}